// Round 9
// baseline (191.729 us; speedup 1.0000x reference)
//
#include <hip/hip_runtime.h>

// NeurTWs R9 = R6 pipeline at the proven launch point + load-issue reorder.
// - GRID 768, __launch_bounds__(256,3): 3 blocks/CU, ALL resident, no tail.
// - NO prefetch rotation (R8 spilled: rotating state overlapped acc's 64
//   AGPRs -> scratch, WRITE 11->47MB), NO reg-cap-4 (R7 spilled).
// - GEMM2 fused algebraically: pe@Wm1_top = h@(W2@Wm1_top)+b2@Wm1_top
//   (no ReLU between GEMM2/GEMM3); tiny make_wfuse kernel precomputes
//   Wfuse[32][64]/bfuse[64] into d_ws once.
// - Load order per iter: kk -> enc FIRST, then ndr -> fA, so GEMM1's
//   s_waitcnt on enc leaves the 8 feat gathers in flight (they're only
//   needed 48 VALU ops + LDS round-trip later).
// - Wave-private LDS h-transpose (writer wave == reader wave, no barrier).
// Fragment layouts (gfx950, verified): A/B: idx=lane&15, k=(lane>>4)*8+j;
// C/D: col=lane&15, row=(lane>>4)*4+reg.

typedef _Float16 half8 __attribute__((ext_vector_type(8)));
typedef float floatx4 __attribute__((ext_vector_type(4)));

#define HSTR 40     // h row stride (f16): 80 B
#define WSTR 104    // bmat row stride (f16): 208 B
#define GRID_MAIN 768

__global__ void feat_to_f16(const float* __restrict__ nf,
                            _Float16* __restrict__ o, int n8) {
    int t = blockIdx.x * 256 + threadIdx.x;
    if (t >= n8) return;
    const float4* p = (const float4*)nf + (size_t)t * 2;
    const float4 a = p[0], b = p[1];
    half8 h;
    h[0] = (_Float16)a.x; h[1] = (_Float16)a.y;
    h[2] = (_Float16)a.z; h[3] = (_Float16)a.w;
    h[4] = (_Float16)b.x; h[5] = (_Float16)b.y;
    h[6] = (_Float16)b.z; h[7] = (_Float16)b.w;
    *((half8*)o + t) = h;
}

// Wfuse[i][c] = sum_n W2[i][n]*Wm1[n][c]; bfuse[c] = bm1[c] + sum_n b2[n]*Wm1[n][c]
__global__ void make_wfuse(const float* __restrict__ W2,
                           const float* __restrict__ Wm1,
                           const float* __restrict__ b2,
                           const float* __restrict__ bm1,
                           float* __restrict__ wfuse,
                           float* __restrict__ bfuse) {
    const int t = threadIdx.x;
    #pragma unroll
    for (int u = 0; u < 8; ++u) {
        const int e = t * 8 + u, i = e >> 6, c = e & 63;
        float s = 0.f;
        #pragma unroll
        for (int n = 0; n < 32; ++n)
            s = fmaf(W2[i * 32 + n], Wm1[n * 64 + c], s);
        wfuse[i * 64 + c] = s;
    }
    if (t < 64) {
        float s = bm1[t];
        #pragma unroll
        for (int n = 0; n < 32; ++n)
            s = fmaf(b2[n], Wm1[n * 64 + t], s);
        bfuse[t] = s;
    }
}

__global__ __launch_bounds__(256, 3) void neurtw_r9(
    const float* __restrict__ pos_table,   // [NUM_KEYS, 4]
    const float* __restrict__ node_feat,   // [NUM_NODES, 64] fp32 (fallback)
    const float* __restrict__ W1,          // [4, 32]
    const float* __restrict__ b1,          // [32]
    const float* __restrict__ Wm1,         // [96, 64]
    const float* __restrict__ Wm2,         // [64, 1]
    const float* __restrict__ bm2,         // [1]
    const int*   __restrict__ key_idx,     // [rows]
    const int*   __restrict__ node_idx,    // [rows]
    const float* __restrict__ wfuse,       // [32, 64] (ws)
    const float* __restrict__ bfuse,       // [64]     (ws)
    const _Float16* __restrict__ feat16,   // [NUM_NODES, 64] f16 (ws)
    int use_f16,
    float*       __restrict__ out,         // [rows]
    int rows)
{
    __shared__ _Float16 hbuf[256 * HSTR];  // 20 KB, wave-private slices
    __shared__ _Float16 bmat[64 * WSTR];   // 13.3 KB  bmat[n][k], K=96 fused

    const int tid  = threadIdx.x;
    const int lane = tid & 63;
    const int r0   = (tid >> 6) * 64;
    const int ln   = lane & 15;
    const int q    = lane >> 4;

    // ---- once per block: stage fused B-matrix [n][k] ----
    #pragma unroll
    for (int i = 0; i < 3; ++i) {
        const int task = i * 256 + tid;
        const int n = task & 63, k8 = task >> 6;
        const float* src = (k8 < 4) ? wfuse : Wm1;   // both [k][64]
        half8 w;
        #pragma unroll
        for (int kk = 0; kk < 8; ++kk)
            w[kk] = (_Float16)src[(k8 * 8 + kk) * 64 + n];
        *(half8*)(&bmat[n * WSTR + k8 * 8]) = w;
    }

    // ---- per-lane loop-invariant fragments ----
    float bfusev[4], wm2v[4];
    #pragma unroll
    for (int ct = 0; ct < 4; ++ct) {
        bfusev[ct] = bfuse[ct * 16 + ln];
        wm2v[ct]   = Wm2[ct * 16 + ln];
    }
    const float bm2s = bm2[0];

    __syncthreads();   // bmat staged (only barrier in the kernel)

    for (int base = blockIdx.x * 256; base < rows; base += GRID_MAIN * 256) {
        const int row = base + tid;

        // ---- issue enc chain FIRST (GEMM1 consumes it first) ----
        const int kk = key_idx[row];
        const float4 enc = *(const float4*)(pos_table + (size_t)kk * 4);

        // ---- then feat chain: needed only after GEMM1 + transpose ----
        int ndr[4];
        #pragma unroll
        for (int rt = 0; rt < 4; ++rt)
            ndr[rt] = node_idx[base + r0 + rt * 16 + ln];

        half8 fA[4][2];
        if (use_f16) {
            #pragma unroll
            for (int rt = 0; rt < 4; ++rt) {
                const _Float16* fb = feat16 + (size_t)ndr[rt] * 64 + q * 8;
                fA[rt][0] = *(const half8*)(fb);
                fA[rt][1] = *(const half8*)(fb + 32);
            }
        } else {
            #pragma unroll
            for (int rt = 0; rt < 4; ++rt) {
                const float* fb = node_feat + (size_t)ndr[rt] * 64 + q * 8;
                #pragma unroll
                for (int kt = 0; kt < 2; ++kt) {
                    const float4 lo = *(const float4*)(fb + kt * 32);
                    const float4 hi = *(const float4*)(fb + kt * 32 + 4);
                    half8 h;
                    h[0] = (_Float16)lo.x; h[1] = (_Float16)lo.y;
                    h[2] = (_Float16)lo.z; h[3] = (_Float16)lo.w;
                    h[4] = (_Float16)hi.x; h[5] = (_Float16)hi.y;
                    h[6] = (_Float16)hi.z; h[7] = (_Float16)hi.w;
                    fA[rt][kt] = h;
                }
            }
        }

        // ---- GEMM1 (fp32 VALU, uniform W1 via s_load) -> hbuf ----
        #pragma unroll
        for (int g = 0; g < 4; ++g) {
            half8 hv;
            #pragma unroll
            for (int j8 = 0; j8 < 8; ++j8) {
                const int j = g * 8 + j8;
                float a = fmaf(enc.w, W1[96 + j],
                          fmaf(enc.z, W1[64 + j],
                          fmaf(enc.y, W1[32 + j],
                          fmaf(enc.x, W1[j], b1[j]))));
                hv[j8] = (_Float16)fmaxf(a, 0.0f);
            }
            *(half8*)(&hbuf[tid * HSTR + g * 8]) = hv;
        }
        // wave-private transpose read — no barrier (same wave wrote it)
        half8 a_h[4];
        #pragma unroll
        for (int rt = 0; rt < 4; ++rt)
            a_h[rt] = *(const half8*)(&hbuf[(r0 + rt * 16 + ln) * HSTR + q * 8]);

        // ---- fused GEMM3: K = 32(h via Wfuse) + 64(feat via Wm1) ----
        floatx4 acc[4][4];
        #pragma unroll
        for (int ct = 0; ct < 4; ++ct) {
            const float bb = bfusev[ct];
            #pragma unroll
            for (int rt = 0; rt < 4; ++rt)
                acc[rt][ct] = (floatx4){bb, bb, bb, bb};
        }

        {   // ktile 0: A = h
            half8 b0[4];
            #pragma unroll
            for (int ct = 0; ct < 4; ++ct)
                b0[ct] = *(const half8*)(&bmat[(ct * 16 + ln) * WSTR + q * 8]);
            #pragma unroll
            for (int rt = 0; rt < 4; ++rt)
                #pragma unroll
                for (int ct = 0; ct < 4; ++ct)
                    acc[rt][ct] = __builtin_amdgcn_mfma_f32_16x16x32_f16(
                        a_h[rt], b0[ct], acc[rt][ct], 0, 0, 0);
        }

        #pragma unroll
        for (int kt = 0; kt < 2; ++kt) {   // ktiles 1,2: A = feat
            half8 bk[4];
            #pragma unroll
            for (int ct = 0; ct < 4; ++ct)
                bk[ct] = *(const half8*)(&bmat[(ct * 16 + ln) * WSTR + 32 + kt * 32 + q * 8]);
            #pragma unroll
            for (int rt = 0; rt < 4; ++rt)
                #pragma unroll
                for (int ct = 0; ct < 4; ++ct)
                    acc[rt][ct] = __builtin_amdgcn_mfma_f32_16x16x32_f16(
                        fA[rt][kt], bk[ct], acc[rt][ct], 0, 0, 0);
        }

        // ---- GEMM4: relu + Wm2 dot + butterfly + store ----
        #pragma unroll
        for (int rt = 0; rt < 4; ++rt) {
            #pragma unroll
            for (int r = 0; r < 4; ++r) {
                float p = 0.0f;
                #pragma unroll
                for (int ct = 0; ct < 4; ++ct)
                    p = fmaf(fmaxf(acc[rt][ct][r], 0.0f), wm2v[ct], p);
                p += __shfl_xor(p, 1);
                p += __shfl_xor(p, 2);
                p += __shfl_xor(p, 4);
                p += __shfl_xor(p, 8);
                if (ln == 0)
                    out[base + r0 + rt * 16 + q * 4 + r] = p + bm2s;
            }
        }
    }
}

extern "C" void kernel_launch(void* const* d_in, const int* in_sizes, int n_in,
                              void* d_out, int out_size, void* d_ws, size_t ws_size,
                              hipStream_t stream) {
    const float* pos_table = (const float*)d_in[0];
    const float* node_feat = (const float*)d_in[1];
    const float* W1        = (const float*)d_in[2];
    const float* b1        = (const float*)d_in[3];
    const float* W2        = (const float*)d_in[4];
    const float* b2        = (const float*)d_in[5];
    const float* Wm1       = (const float*)d_in[6];
    const float* bm1       = (const float*)d_in[7];
    const float* Wm2       = (const float*)d_in[8];
    const float* bm2       = (const float*)d_in[9];
    const int*   key_idx   = (const int*)d_in[10];
    const int*   node_idx  = (const int*)d_in[11];
    float* out = (float*)d_out;

    const int rows  = in_sizes[10];                // 1,048,576
    const int nfeat = in_sizes[1];                 // NUM_NODES*64

    // ws layout: [0,8K) Wfuse f32; [8K,8K+256) bfuse; [16K, ...) feat16
    float*    wfuse  = (float*)d_ws;
    float*    bfuse  = (float*)((char*)d_ws + 8192);
    _Float16* feat16 = (_Float16*)((char*)d_ws + 16384);
    const size_t need_f16 = 16384 + (size_t)nfeat * sizeof(_Float16);
    const int use_f16 = (ws_size >= need_f16) ? 1 : 0;

    if (use_f16) {
        const int n8 = nfeat / 8;
        feat_to_f16<<<(n8 + 255) / 256, 256, 0, stream>>>(node_feat, feat16, n8);
    }
    make_wfuse<<<1, 256, 0, stream>>>(W2, Wm1, b2, bm1, wfuse, bfuse);

    neurtw_r9<<<GRID_MAIN, 256, 0, stream>>>(
        pos_table, node_feat, W1, b1, Wm1, Wm2, bm2,
        key_idx, node_idx, wfuse, bfuse, feat16, use_f16, out, rows);
}

// Round 10
// 157.403 us; speedup vs baseline: 1.2181x; 1.2181x over previous
//
#include <hip/hip_runtime.h>

// NeurTWs R10 = R5 (best measured: 63us, no spill) minus the two per-iter
// __syncthreads. Both LDS round-trips (h-transpose, pe-transpose) touch
// ONLY the wave's own 64-row slice: writer wave == reader wave, DS ops are
// in-order per wave (validated barrier-free in R6/R9 on-device), so the
// barriers only served to serialize the block's 4 waves. nd_lds dropped
// (direct per-lane node_idx loads, proven in R9). Everything else is
// byte-for-byte R5: GEMM2 via MFMA (NOT Wfuse — all Wfuse variants
// R6/R8/R9 generated ~43MB scratch traffic), 768 blocks, bounds(256,3).
// Fragment layouts (gfx950, verified): A/B: idx=lane&15, k=(lane>>4)*8+j;
// C/D: col=lane&15, row=(lane>>4)*4+reg.

typedef _Float16 half8 __attribute__((ext_vector_type(8)));
typedef float floatx4 __attribute__((ext_vector_type(4)));

#define HSTR 40    // h/pe row stride (f16): 80 B
#define WSTR 104   // wm1t row stride (f16): 208 B
#define GRID_MAIN 768

__global__ void feat_to_f16(const float* __restrict__ nf,
                            _Float16* __restrict__ o, int n8) {
    int t = blockIdx.x * 256 + threadIdx.x;
    if (t >= n8) return;
    const float4* p = (const float4*)nf + (size_t)t * 2;
    const float4 a = p[0], b = p[1];
    half8 h;
    h[0] = (_Float16)a.x; h[1] = (_Float16)a.y;
    h[2] = (_Float16)a.z; h[3] = (_Float16)a.w;
    h[4] = (_Float16)b.x; h[5] = (_Float16)b.y;
    h[6] = (_Float16)b.z; h[7] = (_Float16)b.w;
    *((half8*)o + t) = h;
}

__global__ __launch_bounds__(256, 3) void neurtw_r10(
    const float* __restrict__ pos_table,   // [NUM_KEYS, 4]
    const float* __restrict__ node_feat,   // [NUM_NODES, 64] fp32 (fallback)
    const float* __restrict__ W1,          // [4, 32]
    const float* __restrict__ b1,          // [32]
    const float* __restrict__ W2,          // [32, 32]
    const float* __restrict__ b2,          // [32]
    const float* __restrict__ Wm1,         // [96, 64]
    const float* __restrict__ bm1,         // [64]
    const float* __restrict__ Wm2,         // [64, 1]
    const float* __restrict__ bm2,         // [1]
    const int*   __restrict__ key_idx,     // [rows]
    const int*   __restrict__ node_idx,    // [rows]
    const _Float16* __restrict__ feat16,   // [NUM_NODES, 64] f16 (ws)
    int use_f16,
    float*       __restrict__ out,         // [rows]
    int rows)
{
    __shared__ _Float16 hpe[256 * HSTR];   // 20 KB (h then pe; wave-private)
    __shared__ _Float16 wm1t[64 * WSTR];   // 13 KB  wm1t[n][k] = Wm1[k][n]

    const int tid  = threadIdx.x;
    const int lane = tid & 63;
    const int r0   = (tid >> 6) * 64;
    const int ln   = lane & 15;
    const int q    = lane >> 4;

    // ---------- once per block: stage Wm1^T into LDS ----------
    #pragma unroll
    for (int i = 0; i < 3; ++i) {
        const int task = i * 256 + tid;
        const int n = task & 63, k8 = task >> 6;
        half8 w;
        #pragma unroll
        for (int kk = 0; kk < 8; ++kk)
            w[kk] = (_Float16)Wm1[(k8 * 8 + kk) * 64 + n];
        *(half8*)(&wm1t[n * WSTR + k8 * 8]) = w;
    }

    // ---------- once per block: per-lane weight/bias fragments ----------
    half8 b_w2[2];
    #pragma unroll
    for (int ct = 0; ct < 2; ++ct)
        #pragma unroll
        for (int j = 0; j < 8; ++j)
            b_w2[ct][j] = (_Float16)W2[(q * 8 + j) * 32 + ct * 16 + ln];
    float b2v[2];
    b2v[0] = b2[ln]; b2v[1] = b2[16 + ln];
    float bm1v[4], wm2v[4];
    #pragma unroll
    for (int ct = 0; ct < 4; ++ct) {
        bm1v[ct] = bm1[ct * 16 + ln];
        wm2v[ct] = Wm2[ct * 16 + ln];
    }
    const float bm2s = bm2[0];

    __syncthreads();   // wm1t staged (the ONLY barrier in the kernel)

    for (int base = blockIdx.x * 256; base < rows; base += GRID_MAIN * 256) {
        const int row = base + tid;

        // ---- issue all global loads upfront ----
        int ndr[4];
        #pragma unroll
        for (int rt = 0; rt < 4; ++rt)
            ndr[rt] = node_idx[base + r0 + rt * 16 + ln];

        half8 fA[4][2];                    // feat A-fragments (prefetched)
        if (use_f16) {
            #pragma unroll
            for (int rt = 0; rt < 4; ++rt) {
                const _Float16* fb = feat16 + (size_t)ndr[rt] * 64 + q * 8;
                fA[rt][0] = *(const half8*)(fb);
                fA[rt][1] = *(const half8*)(fb + 32);
            }
        } else {
            #pragma unroll
            for (int rt = 0; rt < 4; ++rt) {
                const float* fb = node_feat + (size_t)ndr[rt] * 64 + q * 8;
                #pragma unroll
                for (int kt = 0; kt < 2; ++kt) {
                    const float4 lo = *(const float4*)(fb + kt * 32);
                    const float4 hi = *(const float4*)(fb + kt * 32 + 4);
                    half8 h;
                    h[0] = (_Float16)lo.x; h[1] = (_Float16)lo.y;
                    h[2] = (_Float16)lo.z; h[3] = (_Float16)lo.w;
                    h[4] = (_Float16)hi.x; h[5] = (_Float16)hi.y;
                    h[6] = (_Float16)hi.z; h[7] = (_Float16)hi.w;
                    fA[rt][kt] = h;
                }
            }
        }

        const int kk = key_idx[row];
        const float4 enc = *(const float4*)(pos_table + (size_t)kk * 4);

        // ---- GEMM1 (VALU fp32, uniform weights via s_load) -> h ----
        #pragma unroll
        for (int g = 0; g < 4; ++g) {
            half8 hv;
            #pragma unroll
            for (int j8 = 0; j8 < 8; ++j8) {
                const int j = g * 8 + j8;
                float a = fmaf(enc.w, W1[96 + j],
                          fmaf(enc.z, W1[64 + j],
                          fmaf(enc.y, W1[32 + j],
                          fmaf(enc.x, W1[j], b1[j]))));
                hv[j8] = (_Float16)fmaxf(a, 0.0f);
            }
            *(half8*)(&hpe[tid * HSTR + g * 8]) = hv;
        }
        // wave-private transpose read — no barrier (same wave wrote it)
        half8 a_h[4];
        #pragma unroll
        for (int rt = 0; rt < 4; ++rt)
            a_h[rt] = *(const half8*)(&hpe[(r0 + rt * 16 + ln) * HSTR + q * 8]);

        // ---- GEMM2: 8 MFMA -> pe (C-layout regs) ----
        floatx4 pc[4][2];
        #pragma unroll
        for (int rt = 0; rt < 4; ++rt)
            #pragma unroll
            for (int ct = 0; ct < 2; ++ct) {
                floatx4 c = {0.f, 0.f, 0.f, 0.f};
                pc[rt][ct] = __builtin_amdgcn_mfma_f32_16x16x32_f16(
                    a_h[rt], b_w2[ct], c, 0, 0, 0);
            }

        // write pe into the SAME buffer (h consumed; own wave's slice only)
        #pragma unroll
        for (int rt = 0; rt < 4; ++rt)
            #pragma unroll
            for (int ct = 0; ct < 2; ++ct)
                #pragma unroll
                for (int r = 0; r < 4; ++r)
                    hpe[(r0 + rt * 16 + q * 4 + r) * HSTR + ct * 16 + ln] =
                        (_Float16)(pc[rt][ct][r] + b2v[ct]);
        // no barrier: reader below is the same wave

        // ---- GEMM3: 48 MFMA ----
        floatx4 acc[4][4];
        #pragma unroll
        for (int ct = 0; ct < 4; ++ct) {
            const float bb = bm1v[ct];
            #pragma unroll
            for (int rt = 0; rt < 4; ++rt)
                acc[rt][ct] = (floatx4){bb, bb, bb, bb};
        }

        {   // ktile 0: A = pe from LDS
            half8 a_pe[4];
            #pragma unroll
            for (int rt = 0; rt < 4; ++rt)
                a_pe[rt] = *(const half8*)(&hpe[(r0 + rt * 16 + ln) * HSTR + q * 8]);
            half8 b0[4];
            #pragma unroll
            for (int ct = 0; ct < 4; ++ct)
                b0[ct] = *(const half8*)(&wm1t[(ct * 16 + ln) * WSTR + q * 8]);
            #pragma unroll
            for (int rt = 0; rt < 4; ++rt)
                #pragma unroll
                for (int ct = 0; ct < 4; ++ct)
                    acc[rt][ct] = __builtin_amdgcn_mfma_f32_16x16x32_f16(
                        a_pe[rt], b0[ct], acc[rt][ct], 0, 0, 0);
        }

        #pragma unroll
        for (int kt = 0; kt < 2; ++kt) {   // ktiles 1,2: A = feat (prefetched)
            half8 bk[4];
            #pragma unroll
            for (int ct = 0; ct < 4; ++ct)
                bk[ct] = *(const half8*)(&wm1t[(ct * 16 + ln) * WSTR + 32 + kt * 32 + q * 8]);
            #pragma unroll
            for (int rt = 0; rt < 4; ++rt)
                #pragma unroll
                for (int ct = 0; ct < 4; ++ct)
                    acc[rt][ct] = __builtin_amdgcn_mfma_f32_16x16x32_f16(
                        fA[rt][kt], bk[ct], acc[rt][ct], 0, 0, 0);
        }

        // ---- GEMM4: relu + Wm2 dot + 4-step butterfly + store ----
        #pragma unroll
        for (int rt = 0; rt < 4; ++rt) {
            #pragma unroll
            for (int r = 0; r < 4; ++r) {
                float p = 0.0f;
                #pragma unroll
                for (int ct = 0; ct < 4; ++ct)
                    p = fmaf(fmaxf(acc[rt][ct][r], 0.0f), wm2v[ct], p);
                p += __shfl_xor(p, 1);
                p += __shfl_xor(p, 2);
                p += __shfl_xor(p, 4);
                p += __shfl_xor(p, 8);
                if (ln == 0)
                    out[base + r0 + rt * 16 + q * 4 + r] = p + bm2s;
            }
        }
    }
}

extern "C" void kernel_launch(void* const* d_in, const int* in_sizes, int n_in,
                              void* d_out, int out_size, void* d_ws, size_t ws_size,
                              hipStream_t stream) {
    const float* pos_table = (const float*)d_in[0];
    const float* node_feat = (const float*)d_in[1];
    const float* W1        = (const float*)d_in[2];
    const float* b1        = (const float*)d_in[3];
    const float* W2        = (const float*)d_in[4];
    const float* b2        = (const float*)d_in[5];
    const float* Wm1       = (const float*)d_in[6];
    const float* bm1       = (const float*)d_in[7];
    const float* Wm2       = (const float*)d_in[8];
    const float* bm2       = (const float*)d_in[9];
    const int*   key_idx   = (const int*)d_in[10];
    const int*   node_idx  = (const int*)d_in[11];
    float* out = (float*)d_out;

    const int rows  = in_sizes[10];                // 1,048,576
    const int nfeat = in_sizes[1];                 // NUM_NODES*64

    _Float16* feat16 = (_Float16*)d_ws;
    const size_t need = (size_t)nfeat * sizeof(_Float16);
    const int use_f16 = (ws_size >= need) ? 1 : 0;

    if (use_f16) {
        const int n8 = nfeat / 8;
        feat_to_f16<<<(n8 + 255) / 256, 256, 0, stream>>>(node_feat, feat16, n8);
    }

    neurtw_r10<<<GRID_MAIN, 256, 0, stream>>>(
        pos_table, node_feat, W1, b1, W2, b2, Wm1, bm1, Wm2, bm2,
        key_idx, node_idx, feat16, use_f16, out, rows);
}